// Round 18
// baseline (405.878 us; speedup 1.0000x reference)
//
#include <hip/hip_runtime.h>
#include <math.h>

typedef unsigned short u16;
typedef short bf16x8 __attribute__((ext_vector_type(8)));
typedef float f32x4 __attribute__((ext_vector_type(4)));

#define DEV static __device__ __forceinline__

DEV float bf2f(u16 u) {
  union { unsigned int i; float f; } v; v.i = ((unsigned int)u) << 16; return v.f;
}
DEV u16 f2bf(float f) {
  union { float f; unsigned int i; } v; v.f = f;
  unsigned int x = v.i;
  return (u16)((x + 0x7FFFu + ((x >> 16) & 1u)) >> 16);  // RNE
}

DEV void gload16(const void* gsrc, void* ldst) {
  __builtin_amdgcn_global_load_lds(
      (__attribute__((address_space(1))) void*)gsrc,
      (__attribute__((address_space(3))) void*)ldst, 16, 0, 0);
}

DEV f32x4 mfma16(bf16x8 a, bf16x8 b, f32x4 c) {
  return __builtin_amdgcn_mfma_f32_16x16x32_bf16(a, b, c, 0, 0, 0);
}

// ---------------------------------------------------------------------------
// 8-phase 256-row NT GEMM — R8 structure + sound vmcnt "memory" clobbers
// (R15; pass pre+post). GEMM inner loop frozen since R15; epilogues vary.
// Stage stream (T0=2it, T1=T0+1; vmcnt(6) NFR=4 / vmcnt(4) NFR=2 at ph4/ph8;
// peeled final iteration drains once at ph4):
//  ph1 A(T1,h1) | ph2 B(T0+2,h0) | ph3 A(T0+2,h0) | ph4 B(T0+2,h1)+vm |
//  ph5 A(T0+2,h1) | ph6 B(T0+3,h0) | ph7 B(T0+3,h1) | ph8 A(T0+3,h0)+vm
// EPI: 0 bias, 1 +GELU(exp2-sigmoid), 2 +res(f32), 3 *QSCALE,
//      4 V-direct: write transposed to Vt[b][h][dk][s] (ushort4 per frag).
// ---------------------------------------------------------------------------
template <int EPI, int WF32, int NFR>
__global__ __launch_bounds__(512, 2)
void gemm8(const u16* __restrict__ A, const u16* __restrict__ Bt,
           const float* __restrict__ bias, const float* __restrict__ res,
           void* __restrict__ Cv, int M, int N, int K) {
  constexpr int BN = NFR * 64;
  constexpr int HB = NFR * 4096;  // B half-tile bytes (BN/2 rows x 128B)
  __shared__ __align__(16) char Alds[4 * 16384];
  __shared__ __align__(16) char Blds[4 * HB];

  const int ntn = N / BN;
  const int nwg = gridDim.x;          // multiple of 8 here
  const int cpx = nwg >> 3;
  const int bid = (int)blockIdx.x;
  const int swb = (bid & 7) * cpx + (bid >> 3);  // XCD-bijective swizzle
  const int tm = swb / ntn, tn = swb % ntn;

  const int tid = threadIdx.x;
  const int wave = tid >> 6, lane = tid & 63;
  const int wm = wave >> 2, wn = wave & 3;
  const int lg = lane >> 4, lr = lane & 15;
  const int swx = (lr & 7) << 4;

  f32x4 acc[8][NFR];
#pragma unroll
  for (int m = 0; m < 8; ++m)
#pragma unroll
    for (int n = 0; n < NFR; ++n)
#pragma unroll
      for (int r = 0; r < 4; ++r) acc[m][n][r] = 0.f;

  const size_t rowb = (size_t)K * 2;
  const char* Ab = (const char*)A + (size_t)tm * 256 * rowb;
  const char* Bb = (const char*)Bt + (size_t)tn * BN * rowb;

  int rowS[2], colS[2];
#pragma unroll
  for (int rr = 0; rr < 2; ++rr) {
    const int p = rr * 8192 + tid * 16;
    const int f = p ^ (((p >> 7) & 7) << 4);
    rowS[rr] = f >> 7; colS[rr] = f & 127;
  }

  const int NT = K >> 6;

#define SA(T, H)                                                              \
  do {                                                                        \
    char* d_ = Alds + ((((T) & 1) * 2 + (H)) << 14);                          \
    _Pragma("unroll")                                                         \
    for (int r_ = 0; r_ < 2; ++r_)                                            \
      gload16(Ab + (size_t)((H) * 128 + rowS[r_]) * rowb + (size_t)(T) * 128  \
                  + colS[r_],                                                 \
              d_ + r_ * 8192 + wave * 1024);                                  \
  } while (0)

#define SB(T, H)                                                              \
  do {                                                                        \
    char* d_ = Blds + ((((T) & 1) * 2 + (H)) * HB);                           \
    _Pragma("unroll")                                                         \
    for (int r_ = 0; r_ < NFR / 2; ++r_)                                      \
      gload16(Bb + (size_t)((H) * (BN / 2) + rowS[r_]) * rowb                 \
                  + (size_t)(T) * 128 + colS[r_],                             \
              d_ + r_ * 8192 + wave * 1024);                                  \
  } while (0)

  // DOVM: 0 none, 1 counted (6 for NFR=4 / 4 for NFR=2), 2 drain vmcnt(0)
#define PHASE(SS, Q, STG, DOVM)                                               \
  {                                                                           \
    if ((Q) == 0) {                                                           \
      _Pragma("unroll")                                                       \
      for (int n_ = 0; n_ < NFR; ++n_) {                                      \
        const int g_ = n_ * 4 + wn;                                           \
        const char* bs_ = Blds + ((SS) * 2 + g_ / (NFR * 2)) * HB;            \
        const int rb_ = (g_ % (NFR * 2)) * 16 + lr;                           \
        _Pragma("unroll")                                                     \
        for (int k_ = 0; k_ < 2; ++k_)                                        \
          bfr[n_][k_] =                                                       \
              *(const bf16x8*)(bs_ + ((rb_ * 128 + k_ * 64 + lg * 16) ^ swx));\
      }                                                                       \
    }                                                                         \
    bf16x8 af_[2][2];                                                         \
    {                                                                         \
      const char* as_ = Alds + (((SS) * 2 + ((Q) >> 1)) << 14);               \
      _Pragma("unroll")                                                       \
      for (int j_ = 0; j_ < 2; ++j_) {                                        \
        const int ra_ = ((4 * (Q) + 2 * j_ + wm) & 7) * 16 + lr;              \
        _Pragma("unroll")                                                     \
        for (int k_ = 0; k_ < 2; ++k_)                                        \
          af_[j_][k_] =                                                       \
              *(const bf16x8*)(as_ + ((ra_ * 128 + k_ * 64 + lg * 16) ^ swx));\
      }                                                                       \
    }                                                                         \
    STG;                                                                      \
    if ((Q) == 0) asm volatile("s_waitcnt lgkmcnt(8)");                       \
    if ((DOVM) == 1) {                                                        \
      if (NFR == 4) asm volatile("s_waitcnt vmcnt(6)" ::: "memory");          \
      else          asm volatile("s_waitcnt vmcnt(4)" ::: "memory");          \
    } else if ((DOVM) == 2) {                                                 \
      asm volatile("s_waitcnt vmcnt(0)" ::: "memory");                        \
    }                                                                         \
    __builtin_amdgcn_s_barrier();                                             \
    asm volatile("s_waitcnt lgkmcnt(0)");                                     \
    __builtin_amdgcn_sched_barrier(0);                                        \
    __builtin_amdgcn_s_setprio(1);                                            \
    _Pragma("unroll")                                                         \
    for (int j_ = 0; j_ < 2; ++j_)                                            \
      _Pragma("unroll")                                                       \
      for (int n_ = 0; n_ < NFR; ++n_)                                        \
        _Pragma("unroll")                                                     \
        for (int k_ = 0; k_ < 2; ++k_)                                        \
          acc[2 * (Q) + j_][n_] =                                             \
              mfma16(af_[j_][k_], bfr[n_][k_], acc[2 * (Q) + j_][n_]);        \
    __builtin_amdgcn_s_setprio(0);                                            \
    __builtin_amdgcn_s_barrier();                                             \
  }

  // prologue: tile0 complete + tile1 {A h0, B h0, B h1}; A(1,h1) at ph1.
  SA(0, 0); SA(0, 1); SB(0, 0); SB(0, 1); SA(1, 0); SB(1, 0); SB(1, 1);
  asm volatile("s_waitcnt vmcnt(0)" ::: "memory");
  __builtin_amdgcn_s_barrier();

  bf16x8 bfr[NFR][2];
  const int NIT = NT >> 1;
  for (int it = 0; it < NIT - 1; ++it) {
    const int T0 = 2 * it;
    PHASE(0, 0, SA(T0 + 1, 1), 0)
    PHASE(0, 1, SB(T0 + 2, 0), 0)
    PHASE(0, 2, SA(T0 + 2, 0), 0)
    PHASE(0, 3, SB(T0 + 2, 1), 1)
    PHASE(1, 0, SA(T0 + 2, 1), 0)
    PHASE(1, 1, SB(T0 + 3, 0), 0)
    PHASE(1, 2, SB(T0 + 3, 1), 0)
    PHASE(1, 3, SA(T0 + 3, 0), 1)
  }
  {  // peeled final iteration: stage only A(NT-1,h1); drain at ph4
    const int T0 = NT - 2;
    PHASE(0, 0, SA(T0 + 1, 1), 0)
    PHASE(0, 1, ((void)0), 0)
    PHASE(0, 2, ((void)0), 0)
    PHASE(0, 3, ((void)0), 2)
    PHASE(1, 0, ((void)0), 0)
    PHASE(1, 1, ((void)0), 0)
    PHASE(1, 2, ((void)0), 0)
    PHASE(1, 3, ((void)0), 0)
  }
#undef SA
#undef SB
#undef PHASE

  // Epilogue. D frag layout: row=(lane>>4)*4+r, col=lane&15 (verified).
#pragma unroll
  for (int m = 0; m < 8; ++m)
#pragma unroll
    for (int n = 0; n < NFR; ++n) {
      const int col = tn * BN + (n * 4 + wn) * 16 + lr;
      const float bc = bias[col];
      if (EPI == 4) {
        // V-direct: 4 r-values are 4 consecutive s positions -> one ushort4
        // at Vt[((b*16 + h)*64 + dk)*1024 + s0], 8B-aligned.
        const int row0 = tm * 256 + (2 * m + wm) * 16 + lg * 4;
        ushort4 o;
        o.x = f2bf(acc[m][n][0] + bc);
        o.y = f2bf(acc[m][n][1] + bc);
        o.z = f2bf(acc[m][n][2] + bc);
        o.w = f2bf(acc[m][n][3] + bc);
        const int b_ = row0 >> 10, s0 = row0 & 1023;
        u16* dst = (u16*)Cv +
                   ((size_t)((b_ << 4) + (col >> 6)) * 64 + (col & 63)) * 1024 + s0;
        *(ushort4*)dst = o;
        continue;
      }
#pragma unroll
      for (int r = 0; r < 4; ++r) {
        const int row = tm * 256 + (2 * m + wm) * 16 + lg * 4 + r;
        float vv = acc[m][n][r] + bc;
        if (EPI == 1) {
          // gelu_tanh(u) == u * sigmoid(2*c*(u+0.044715u^3)); exp2 domain.
          const float u = vv;
          const float z = u + 0.044715f * u * u * u;
          vv = u * __builtin_amdgcn_rcpf(1.0f + exp2f(-2.3022076954f * z));
        } else if (EPI == 2) {
          vv += res[(size_t)row * N + col];
        } else if (EPI == 3) {
          vv *= 0.180336880111112f;  // 0.125 * log2(e)
        }
        if (WF32)
          ((float*)Cv)[(size_t)row * N + col] = vv;
        else
          ((u16*)Cv)[(size_t)row * N + col] = f2bf(vv);
      }
    }
}

// ---------------------------------------------------------------------------
// Flash attention v5: QBLK=128 (8 waves/wg, grid 1024). Per-wave work is
// identical to v4 (16 q-rows, fixed-max exp2 softmax, swapped QK^T, cvt_pk
// P-pack); what changed: one staged K/V stream now feeds 128 q-rows (half
// the DMA per q-row) and LDS = 48KB -> 3 wg x 8 waves = 24 waves/CU (75%
// occupancy cap, up from 50%) to hide tile-boundary latency.
// ---------------------------------------------------------------------------
__global__ __launch_bounds__(512, 6)
void attn_kernel(const u16* __restrict__ Q, const u16* __restrict__ Km,
                 const u16* __restrict__ Vt, const u16* __restrict__ maskT4,
                 u16* __restrict__ O) {
  const int bid = (int)blockIdx.x;
  const int swz = (bid & 7) * 128 + (bid >> 3);  // 1024 % 8 == 0: bijective
  const int qb = swz & 7;
  const int bh = swz >> 3;
  const int b = bh >> 4, h = bh & 15;
  const int wave = threadIdx.x >> 6, lane = threadIdx.x & 63;
  const int lg = lane >> 4, lr = lane & 15;
  __shared__ __align__(16) u16 Ksm[2][64 * 64];   // 16KB
  __shared__ __align__(16) u16 Vsm[2][64 * 64];   // 16KB
  __shared__ __align__(16) u16 Pl[8][1024];       // 16KB
  char* Pb = (char*)&Pl[wave][0];
  const int swx = (lr & 7) << 4;

  const int q0 = qb * 128 + wave * 16;
  const u16* Qp = Q + ((size_t)(b * 1024 + q0)) * 1024 + h * 64;
  bf16x8 qf[2];
#pragma unroll
  for (int ks = 0; ks < 2; ++ks)
    qf[ks] = *(const bf16x8*)(Qp + (size_t)lr * 1024 + ks * 32 + lg * 8);

  float l = 0.f;
  f32x4 accO[4];
#pragma unroll
  for (int fc = 0; fc < 4; ++fc)
#pragma unroll
    for (int r = 0; r < 4; ++r) accO[fc][r] = 0.f;

  const char* Kg = (const char*)(Km + (size_t)(b * 1024) * 1024 + h * 64);
  const char* Vg = (const char*)(Vt + (size_t)(bh * 64) * 1024);
  const ushort4* Mb0 = (const ushort4*)maskT4 + (size_t)b * 256 * 1024 + q0 + lr;

  // 8 waves x 1KB chunk each per K and V tile (wave-uniform LDS base).
#define STAGE_KV(T, BUF)                                                      \
  {                                                                           \
    const int kb_ = (T) * 64;                                                 \
    const int p = wave * 1024 + lane * 16;                                    \
    const int f = p ^ (((p >> 7) & 7) << 4);                                  \
    const int row = f >> 7, colb = f & 127;                                   \
    gload16(Kg + (size_t)(kb_ + row) * 2048 + colb,                           \
            (char*)Ksm[BUF] + wave * 1024);                                   \
    gload16(Vg + (size_t)row * 2048 + (size_t)kb_ * 2 + colb,                 \
            (char*)Vsm[BUF] + wave * 1024);                                   \
  }

  STAGE_KV(0, 0);
  __syncthreads();

  for (int t = 0; t < 16; ++t) {
    const int cb = t & 1;
    if (t < 15) STAGE_KV(t + 1, cb ^ 1);

    ushort4 mv[4];
#pragma unroll
    for (int fc = 0; fc < 4; ++fc)
      mv[fc] = Mb0[(size_t)(t * 16 + fc * 4 + lg) * 1024];

    f32x4 ts[4];
#pragma unroll
    for (int fc = 0; fc < 4; ++fc)
#pragma unroll
      for (int r = 0; r < 4; ++r) ts[fc][r] = 0.f;
    __builtin_amdgcn_s_setprio(1);
#pragma unroll
    for (int ks = 0; ks < 2; ++ks)
#pragma unroll
      for (int fc = 0; fc < 4; ++fc) {
        const int row = fc * 16 + lr;
        const int ad = ((row << 7) | (ks * 64 + lg * 16)) ^ ((row & 7) << 4);
        const bf16x8 kfr = *(const bf16x8*)((const char*)Ksm[cb] + ad);
        ts[fc] = mfma16(kfr, qf[ks], ts[fc]);
      }
    __builtin_amdgcn_s_setprio(0);

#pragma unroll
    for (int fc = 0; fc < 4; ++fc) {
      const float p0 = exp2f(ts[fc][0] + bf2f(mv[fc].x));
      const float p1 = exp2f(ts[fc][1] + bf2f(mv[fc].y));
      const float p2 = exp2f(ts[fc][2] + bf2f(mv[fc].z));
      const float p3 = exp2f(ts[fc][3] + bf2f(mv[fc].w));
      l += (p0 + p1) + (p2 + p3);
      unsigned int w0, w1;
      asm("v_cvt_pk_bf16_f32 %0, %1, %2" : "=v"(w0) : "v"(p0), "v"(p1));
      asm("v_cvt_pk_bf16_f32 %0, %1, %2" : "=v"(w1) : "v"(p2), "v"(p3));
      const int base = lr * 128 + fc * 32 + lg * 8;
      *(unsigned int*)(Pb + ((base + 0) ^ swx)) = w0;
      *(unsigned int*)(Pb + ((base + 4) ^ swx)) = w1;
    }

    __builtin_amdgcn_s_setprio(1);
#pragma unroll
    for (int ks = 0; ks < 2; ++ks) {
      const int ad = (lr * 128 + ks * 64 + lg * 16) ^ swx;
      const bf16x8 pa = *(const bf16x8*)(Pb + ad);
#pragma unroll
      for (int fc = 0; fc < 4; ++fc) {
        const int row = fc * 16 + lr;
        const int vad = ((row << 7) | (ks * 64 + lg * 16)) ^ ((row & 7) << 4);
        const bf16x8 vfr = *(const bf16x8*)((const char*)Vsm[cb] + vad);
        accO[fc] = mfma16(pa, vfr, accO[fc]);
      }
    }
    __builtin_amdgcn_s_setprio(0);

    __syncthreads();
  }

  l += __shfl_xor(l, 16);
  l += __shfl_xor(l, 32);
  float linv[4];
#pragma unroll
  for (int r = 0; r < 4; ++r) linv[r] = 1.0f / __shfl(l, lg * 4 + r);

  u16* Op = O + ((size_t)(b * 1024 + q0)) * 1024 + h * 64;
#pragma unroll
  for (int fc = 0; fc < 4; ++fc)
#pragma unroll
    for (int r = 0; r < 4; ++r)
      Op[(size_t)(lg * 4 + r) * 1024 + fc * 16 + lr] = f2bf(accO[fc][r] * linv[r]);
#undef STAGE_KV
}

// ---------------------------------------------------------------------------
// Fused transpose of the four 1024x1024 weights (f32 -> bf16, transposed).
// ---------------------------------------------------------------------------
__global__ __launch_bounds__(256)
void transpose4_kernel(const float* __restrict__ Wq, const float* __restrict__ Wk,
                       const float* __restrict__ Wv, const float* __restrict__ Wo,
                       u16* __restrict__ wqt, u16* __restrict__ wkt,
                       u16* __restrict__ wvt, u16* __restrict__ wot) {
  const int w = blockIdx.x >> 8, tile = blockIdx.x & 255;
  const float* in = (w == 0) ? Wq : (w == 1) ? Wk : (w == 2) ? Wv : Wo;
  u16* out = (w == 0) ? wqt : (w == 1) ? wkt : (w == 2) ? wvt : wot;
  __shared__ u16 t[64][65];
  const int bx = tile & 15, by = tile >> 4;
  const int tc = threadIdx.x & 63, t4 = threadIdx.x >> 6;
#pragma unroll
  for (int i = 0; i < 16; ++i) {
    const int r = i * 4 + t4;
    t[r][tc] = f2bf(in[(size_t)(by * 64 + r) * 1024 + bx * 64 + tc]);
  }
  __syncthreads();
#pragma unroll
  for (int i = 0; i < 16; ++i) {
    const int r = i * 4 + t4;
    out[(size_t)(bx * 64 + r) * 1024 + by * 64 + tc] = t[tc][r];
  }
}

// 64x64-tiled transpose + f32->bf16 cast: out[C][R] = bf16(in[R][C]^T)
__global__ __launch_bounds__(256)
void transpose_cast(const float* __restrict__ in, u16* __restrict__ out, int R, int C) {
  __shared__ u16 t[64][65];
  const int ctiles = C >> 6;
  const int bx = blockIdx.x % ctiles, by = blockIdx.x / ctiles;
  const int tc = threadIdx.x & 63, t4 = threadIdx.x >> 6;
#pragma unroll
  for (int i = 0; i < 16; ++i) {
    const int r = i * 4 + t4;
    t[r][tc] = f2bf(in[(size_t)(by * 64 + r) * C + bx * 64 + tc]);
  }
  __syncthreads();
#pragma unroll
  for (int i = 0; i < 16; ++i) {
    const int r = i * 4 + t4;
    out[(size_t)(bx * 64 + r) * R + by * 64 + tc] = t[tc][r];
  }
}

// int32 mask -> transposed interleaved additive-bf16 (exp2 domain)
__global__ __launch_bounds__(256)
void mask_t_kernel(const int* __restrict__ mask, u16* __restrict__ mt) {
  const int bt = blockIdx.x;
  const int b = bt >> 8;
  const int kt = (bt >> 4) & 15;
  const int qt = bt & 15;
  __shared__ u16 t[64][65];
  const int tc = threadIdx.x & 63, t4 = threadIdx.x >> 6;
  const u16 neg = f2bf(-1.442695040888963e9f);
  const int* src = mask + ((size_t)b * 1024 + qt * 64) * 1024 + kt * 64;
#pragma unroll
  for (int i = 0; i < 16; ++i) {
    const int q = i * 4 + t4;
    t[q][tc] = src[(size_t)q * 1024 + tc] ? (u16)0 : neg;
  }
  __syncthreads();
  ushort4* dst = (ushort4*)mt + ((size_t)b * 256 + kt * 16) * 1024 + qt * 64;
#pragma unroll
  for (int i = 0; i < 4; ++i) {
    const int kg = i * 4 + t4;
    ushort4 o;
    o.x = t[tc][kg * 4 + 0];
    o.y = t[tc][kg * 4 + 1];
    o.z = t[tc][kg * 4 + 2];
    o.w = t[tc][kg * 4 + 3];
    dst[(size_t)kg * 1024 + tc] = o;
  }
}

// Row LayerNorm over D=1024: f32 in, f32 gains, bf16 out
__global__ __launch_bounds__(256)
void ln_kernel(const float* __restrict__ x, const float* __restrict__ g,
               const float* __restrict__ bb, u16* __restrict__ y) {
  const int row = blockIdx.x, tid = threadIdx.x;
  const float4 v = ((const float4*)(x + (size_t)row * 1024))[tid];
  float s = v.x + v.y + v.z + v.w;
  float ss = v.x * v.x + v.y * v.y + v.z * v.z + v.w * v.w;
#pragma unroll
  for (int mk = 1; mk < 64; mk <<= 1) {
    s += __shfl_xor(s, mk);
    ss += __shfl_xor(ss, mk);
  }
  __shared__ float sa[4], sq[4];
  const int wave = tid >> 6, lane = tid & 63;
  if (lane == 0) { sa[wave] = s; sq[wave] = ss; }
  __syncthreads();
  s = sa[0] + sa[1] + sa[2] + sa[3];
  ss = sq[0] + sq[1] + sq[2] + sq[3];
  const float mu = s * 0.0009765625f;
  const float var = ss * 0.0009765625f - mu * mu;
  const float inv = rsqrtf(var + 1e-5f);
  const float4 gg = ((const float4*)g)[tid];
  const float4 bv = ((const float4*)bb)[tid];
  ushort4 o;
  o.x = f2bf((v.x - mu) * inv * gg.x + bv.x);
  o.y = f2bf((v.y - mu) * inv * gg.y + bv.y);
  o.z = f2bf((v.z - mu) * inv * gg.z + bv.z);
  o.w = f2bf((v.w - mu) * inv * gg.w + bv.w);
  *(ushort4*)(y + (size_t)row * 1024 + tid * 4) = o;
}

extern "C" void kernel_launch(void* const* d_in, const int* in_sizes, int n_in,
                              void* d_out, int out_size, void* d_ws, size_t ws_size,
                              hipStream_t stream) {
  (void)in_sizes; (void)n_in; (void)out_size; (void)ws_size;
  const float* x  = (const float*)d_in[0];
  const int* mask = (const int*)d_in[1];
  const float* Wq = (const float*)d_in[2];  const float* bq = (const float*)d_in[3];
  const float* Wk = (const float*)d_in[4];  const float* bk = (const float*)d_in[5];
  const float* Wv = (const float*)d_in[6];  const float* bv = (const float*)d_in[7];
  const float* Wo = (const float*)d_in[8];  const float* bo = (const float*)d_in[9];
  const float* W1 = (const float*)d_in[10]; const float* b1 = (const float*)d_in[11];
  const float* W2 = (const float*)d_in[12]; const float* b2 = (const float*)d_in[13];
  const float* g1 = (const float*)d_in[14]; const float* be1 = (const float*)d_in[15];
  const float* g2 = (const float*)d_in[16]; const float* be2 = (const float*)d_in[17];

  float* out = (float*)d_out;  // f32 residual stream x2 lives here

  u16* ws = (u16*)d_ws;
  const size_t M1 = (size_t)1024 * 1024;
  u16* y    = ws;
  u16* q    = ws + 8 * M1;
  u16* kbuf = ws + 16 * M1;
  u16* vbuf = ws + 24 * M1;      // attention output
  u16* vt   = ws + 32 * M1;      // V written transposed by the V-GEMM
  u16* hbuf = ws + 8 * M1;       // FFN mid over dead q/k/vbuf/vt
  u16* wqt  = ws + 40 * M1;
  u16* wkt  = ws + 41 * M1;
  u16* wvt  = ws + 42 * M1;
  u16* wot  = ws + 43 * M1;
  u16* w1t  = ws + 44 * M1;
  u16* w2t  = ws + 48 * M1;
  u16* maskT4 = y;               // mask lives in y while y is dead

  dim3 blk(256);
  dim3 blk8(512);
  transpose4_kernel<<<1024, blk, 0, stream>>>(Wq, Wk, Wv, Wo, wqt, wkt, wvt, wot);
  transpose_cast<<<1024, blk, 0, stream>>>(W1, w1t, 1024, 4096);
  transpose_cast<<<1024, blk, 0, stream>>>(W2, w2t, 4096, 1024);
  ln_kernel<<<8192, blk, 0, stream>>>(x, g1, be1, y);
  gemm8<3, 0, 2><<<256, blk8, 0, stream>>>(y, wqt, bq, nullptr, q, 8192, 1024, 1024);
  gemm8<0, 0, 2><<<256, blk8, 0, stream>>>(y, wkt, bk, nullptr, kbuf, 8192, 1024, 1024);
  gemm8<4, 0, 2><<<256, blk8, 0, stream>>>(y, wvt, bv, nullptr, vt, 8192, 1024, 1024);
  mask_t_kernel<<<2048, blk, 0, stream>>>(mask, maskT4);
  attn_kernel<<<1024, blk8, 0, stream>>>(q, kbuf, vt, maskT4, vbuf);
  gemm8<2, 1, 2><<<256, blk8, 0, stream>>>(vbuf, wot, bo, x, out, 8192, 1024, 1024);
  ln_kernel<<<8192, blk, 0, stream>>>(out, g2, be2, y);
  gemm8<1, 0, 4><<<512, blk8, 0, stream>>>(y, w1t, b1, nullptr, hbuf, 8192, 4096, 1024);
  gemm8<2, 1, 2><<<256, blk8, 0, stream>>>(hbuf, w2t, b2, out, out, 8192, 1024, 4096);
}

// Round 19
// 384.536 us; speedup vs baseline: 1.0555x; 1.0555x over previous
//
#include <hip/hip_runtime.h>
#include <math.h>

typedef unsigned short u16;
typedef short bf16x8 __attribute__((ext_vector_type(8)));
typedef float f32x4 __attribute__((ext_vector_type(4)));

#define DEV static __device__ __forceinline__

DEV float bf2f(u16 u) {
  union { unsigned int i; float f; } v; v.i = ((unsigned int)u) << 16; return v.f;
}
DEV u16 f2bf(float f) {
  union { float f; unsigned int i; } v; v.f = f;
  unsigned int x = v.i;
  return (u16)((x + 0x7FFFu + ((x >> 16) & 1u)) >> 16);  // RNE
}

DEV void gload16(const void* gsrc, void* ldst) {
  __builtin_amdgcn_global_load_lds(
      (__attribute__((address_space(1))) void*)gsrc,
      (__attribute__((address_space(3))) void*)ldst, 16, 0, 0);
}

DEV f32x4 mfma16(bf16x8 a, bf16x8 b, f32x4 c) {
  return __builtin_amdgcn_mfma_f32_16x16x32_bf16(a, b, c, 0, 0, 0);
}

// ---------------------------------------------------------------------------
// 8-phase 256-row NT GEMM — R8 structure + sound vmcnt "memory" clobbers
// (R15; pass pre+post). GEMM inner loop frozen since R15; epilogues vary.
// Stage stream (T0=2it, T1=T0+1; vmcnt(6) NFR=4 / vmcnt(4) NFR=2 at ph4/ph8;
// peeled final iteration drains once at ph4):
//  ph1 A(T1,h1) | ph2 B(T0+2,h0) | ph3 A(T0+2,h0) | ph4 B(T0+2,h1)+vm |
//  ph5 A(T0+2,h1) | ph6 B(T0+3,h0) | ph7 B(T0+3,h1) | ph8 A(T0+3,h0)+vm
// EPI: 0 bias, 1 +GELU(exp2-sigmoid), 2 +res(f32), 3 *QSCALE,
//      4 V-direct: write transposed to Vt[b][h][dk][s] (ushort4 per frag).
// ---------------------------------------------------------------------------
template <int EPI, int WF32, int NFR>
__global__ __launch_bounds__(512, 2)
void gemm8(const u16* __restrict__ A, const u16* __restrict__ Bt,
           const float* __restrict__ bias, const float* __restrict__ res,
           void* __restrict__ Cv, int M, int N, int K) {
  constexpr int BN = NFR * 64;
  constexpr int HB = NFR * 4096;  // B half-tile bytes (BN/2 rows x 128B)
  __shared__ __align__(16) char Alds[4 * 16384];
  __shared__ __align__(16) char Blds[4 * HB];

  const int ntn = N / BN;
  const int nwg = gridDim.x;          // multiple of 8 here
  const int cpx = nwg >> 3;
  const int bid = (int)blockIdx.x;
  const int swb = (bid & 7) * cpx + (bid >> 3);  // XCD-bijective swizzle
  const int tm = swb / ntn, tn = swb % ntn;

  const int tid = threadIdx.x;
  const int wave = tid >> 6, lane = tid & 63;
  const int wm = wave >> 2, wn = wave & 3;
  const int lg = lane >> 4, lr = lane & 15;
  const int swx = (lr & 7) << 4;

  f32x4 acc[8][NFR];
#pragma unroll
  for (int m = 0; m < 8; ++m)
#pragma unroll
    for (int n = 0; n < NFR; ++n)
#pragma unroll
      for (int r = 0; r < 4; ++r) acc[m][n][r] = 0.f;

  const size_t rowb = (size_t)K * 2;
  const char* Ab = (const char*)A + (size_t)tm * 256 * rowb;
  const char* Bb = (const char*)Bt + (size_t)tn * BN * rowb;

  int rowS[2], colS[2];
#pragma unroll
  for (int rr = 0; rr < 2; ++rr) {
    const int p = rr * 8192 + tid * 16;
    const int f = p ^ (((p >> 7) & 7) << 4);
    rowS[rr] = f >> 7; colS[rr] = f & 127;
  }

  const int NT = K >> 6;

#define SA(T, H)                                                              \
  do {                                                                        \
    char* d_ = Alds + ((((T) & 1) * 2 + (H)) << 14);                          \
    _Pragma("unroll")                                                         \
    for (int r_ = 0; r_ < 2; ++r_)                                            \
      gload16(Ab + (size_t)((H) * 128 + rowS[r_]) * rowb + (size_t)(T) * 128  \
                  + colS[r_],                                                 \
              d_ + r_ * 8192 + wave * 1024);                                  \
  } while (0)

#define SB(T, H)                                                              \
  do {                                                                        \
    char* d_ = Blds + ((((T) & 1) * 2 + (H)) * HB);                           \
    _Pragma("unroll")                                                         \
    for (int r_ = 0; r_ < NFR / 2; ++r_)                                      \
      gload16(Bb + (size_t)((H) * (BN / 2) + rowS[r_]) * rowb                 \
                  + (size_t)(T) * 128 + colS[r_],                             \
              d_ + r_ * 8192 + wave * 1024);                                  \
  } while (0)

  // DOVM: 0 none, 1 counted (6 for NFR=4 / 4 for NFR=2), 2 drain vmcnt(0)
#define PHASE(SS, Q, STG, DOVM)                                               \
  {                                                                           \
    if ((Q) == 0) {                                                           \
      _Pragma("unroll")                                                       \
      for (int n_ = 0; n_ < NFR; ++n_) {                                      \
        const int g_ = n_ * 4 + wn;                                           \
        const char* bs_ = Blds + ((SS) * 2 + g_ / (NFR * 2)) * HB;            \
        const int rb_ = (g_ % (NFR * 2)) * 16 + lr;                           \
        _Pragma("unroll")                                                     \
        for (int k_ = 0; k_ < 2; ++k_)                                        \
          bfr[n_][k_] =                                                       \
              *(const bf16x8*)(bs_ + ((rb_ * 128 + k_ * 64 + lg * 16) ^ swx));\
      }                                                                       \
    }                                                                         \
    bf16x8 af_[2][2];                                                         \
    {                                                                         \
      const char* as_ = Alds + (((SS) * 2 + ((Q) >> 1)) << 14);               \
      _Pragma("unroll")                                                       \
      for (int j_ = 0; j_ < 2; ++j_) {                                        \
        const int ra_ = ((4 * (Q) + 2 * j_ + wm) & 7) * 16 + lr;              \
        _Pragma("unroll")                                                     \
        for (int k_ = 0; k_ < 2; ++k_)                                        \
          af_[j_][k_] =                                                       \
              *(const bf16x8*)(as_ + ((ra_ * 128 + k_ * 64 + lg * 16) ^ swx));\
      }                                                                       \
    }                                                                         \
    STG;                                                                      \
    if ((Q) == 0) asm volatile("s_waitcnt lgkmcnt(8)");                       \
    if ((DOVM) == 1) {                                                        \
      if (NFR == 4) asm volatile("s_waitcnt vmcnt(6)" ::: "memory");          \
      else          asm volatile("s_waitcnt vmcnt(4)" ::: "memory");          \
    } else if ((DOVM) == 2) {                                                 \
      asm volatile("s_waitcnt vmcnt(0)" ::: "memory");                        \
    }                                                                         \
    __builtin_amdgcn_s_barrier();                                             \
    asm volatile("s_waitcnt lgkmcnt(0)");                                     \
    __builtin_amdgcn_sched_barrier(0);                                        \
    __builtin_amdgcn_s_setprio(1);                                            \
    _Pragma("unroll")                                                         \
    for (int j_ = 0; j_ < 2; ++j_)                                            \
      _Pragma("unroll")                                                       \
      for (int n_ = 0; n_ < NFR; ++n_)                                        \
        _Pragma("unroll")                                                     \
        for (int k_ = 0; k_ < 2; ++k_)                                        \
          acc[2 * (Q) + j_][n_] =                                             \
              mfma16(af_[j_][k_], bfr[n_][k_], acc[2 * (Q) + j_][n_]);        \
    __builtin_amdgcn_s_setprio(0);                                            \
    __builtin_amdgcn_s_barrier();                                             \
  }

  // prologue: tile0 complete + tile1 {A h0, B h0, B h1}; A(1,h1) at ph1.
  SA(0, 0); SA(0, 1); SB(0, 0); SB(0, 1); SA(1, 0); SB(1, 0); SB(1, 1);
  asm volatile("s_waitcnt vmcnt(0)" ::: "memory");
  __builtin_amdgcn_s_barrier();

  bf16x8 bfr[NFR][2];
  const int NIT = NT >> 1;
  for (int it = 0; it < NIT - 1; ++it) {
    const int T0 = 2 * it;
    PHASE(0, 0, SA(T0 + 1, 1), 0)
    PHASE(0, 1, SB(T0 + 2, 0), 0)
    PHASE(0, 2, SA(T0 + 2, 0), 0)
    PHASE(0, 3, SB(T0 + 2, 1), 1)
    PHASE(1, 0, SA(T0 + 2, 1), 0)
    PHASE(1, 1, SB(T0 + 3, 0), 0)
    PHASE(1, 2, SB(T0 + 3, 1), 0)
    PHASE(1, 3, SA(T0 + 3, 0), 1)
  }
  {  // peeled final iteration: stage only A(NT-1,h1); drain at ph4
    const int T0 = NT - 2;
    PHASE(0, 0, SA(T0 + 1, 1), 0)
    PHASE(0, 1, ((void)0), 0)
    PHASE(0, 2, ((void)0), 0)
    PHASE(0, 3, ((void)0), 2)
    PHASE(1, 0, ((void)0), 0)
    PHASE(1, 1, ((void)0), 0)
    PHASE(1, 2, ((void)0), 0)
    PHASE(1, 3, ((void)0), 0)
  }
#undef SA
#undef SB
#undef PHASE

  // Epilogue. D frag layout: row=(lane>>4)*4+r, col=lane&15 (verified).
#pragma unroll
  for (int m = 0; m < 8; ++m)
#pragma unroll
    for (int n = 0; n < NFR; ++n) {
      const int col = tn * BN + (n * 4 + wn) * 16 + lr;
      const float bc = bias[col];
      if (EPI == 4) {
        // V-direct: 4 r-values are 4 consecutive s positions -> one ushort4
        // at Vt[((b*16 + h)*64 + dk)*1024 + s0], 8B-aligned.
        const int row0 = tm * 256 + (2 * m + wm) * 16 + lg * 4;
        ushort4 o;
        o.x = f2bf(acc[m][n][0] + bc);
        o.y = f2bf(acc[m][n][1] + bc);
        o.z = f2bf(acc[m][n][2] + bc);
        o.w = f2bf(acc[m][n][3] + bc);
        const int b_ = row0 >> 10, s0 = row0 & 1023;
        u16* dst = (u16*)Cv +
                   ((size_t)((b_ << 4) + (col >> 6)) * 64 + (col & 63)) * 1024 + s0;
        *(ushort4*)dst = o;
        continue;
      }
#pragma unroll
      for (int r = 0; r < 4; ++r) {
        const int row = tm * 256 + (2 * m + wm) * 16 + lg * 4 + r;
        float vv = acc[m][n][r] + bc;
        if (EPI == 1) {
          // gelu_tanh(u) == u * sigmoid(2*c*(u+0.044715u^3)); exp2 domain.
          const float u = vv;
          const float z = u + 0.044715f * u * u * u;
          vv = u * __builtin_amdgcn_rcpf(1.0f + exp2f(-2.3022076954f * z));
        } else if (EPI == 2) {
          vv += res[(size_t)row * N + col];
        } else if (EPI == 3) {
          vv *= 0.180336880111112f;  // 0.125 * log2(e)
        }
        if (WF32)
          ((float*)Cv)[(size_t)row * N + col] = vv;
        else
          ((u16*)Cv)[(size_t)row * N + col] = f2bf(vv);
      }
    }
}

// ---------------------------------------------------------------------------
// Flash attention v5b: QBLK=128, 8 waves/wg, grid 1024. R18's regression was
// __launch_bounds__(512,6): the 6-waves/EU demand capped VGPR at ~42 for a
// ~60-VGPR body -> scratch spills (+24MB writes, +16MB reads). (512,4) caps
// at 64 VGPR (body fits, zero spill); occupancy is then LDS-limited at
// 3 wg x 8 waves = 24 waves/CU (75%) — the cap we actually wanted.
// ---------------------------------------------------------------------------
__global__ __launch_bounds__(512, 4)
void attn_kernel(const u16* __restrict__ Q, const u16* __restrict__ Km,
                 const u16* __restrict__ Vt, const u16* __restrict__ maskT4,
                 u16* __restrict__ O) {
  const int bid = (int)blockIdx.x;
  const int swz = (bid & 7) * 128 + (bid >> 3);  // 1024 % 8 == 0: bijective
  const int qb = swz & 7;
  const int bh = swz >> 3;
  const int b = bh >> 4, h = bh & 15;
  const int wave = threadIdx.x >> 6, lane = threadIdx.x & 63;
  const int lg = lane >> 4, lr = lane & 15;
  __shared__ __align__(16) u16 Ksm[2][64 * 64];   // 16KB
  __shared__ __align__(16) u16 Vsm[2][64 * 64];   // 16KB
  __shared__ __align__(16) u16 Pl[8][1024];       // 16KB
  char* Pb = (char*)&Pl[wave][0];
  const int swx = (lr & 7) << 4;

  const int q0 = qb * 128 + wave * 16;
  const u16* Qp = Q + ((size_t)(b * 1024 + q0)) * 1024 + h * 64;
  bf16x8 qf[2];
#pragma unroll
  for (int ks = 0; ks < 2; ++ks)
    qf[ks] = *(const bf16x8*)(Qp + (size_t)lr * 1024 + ks * 32 + lg * 8);

  float l = 0.f;
  f32x4 accO[4];
#pragma unroll
  for (int fc = 0; fc < 4; ++fc)
#pragma unroll
    for (int r = 0; r < 4; ++r) accO[fc][r] = 0.f;

  const char* Kg = (const char*)(Km + (size_t)(b * 1024) * 1024 + h * 64);
  const char* Vg = (const char*)(Vt + (size_t)(bh * 64) * 1024);
  const ushort4* Mb0 = (const ushort4*)maskT4 + (size_t)b * 256 * 1024 + q0 + lr;

  // 8 waves x 1KB chunk each per K and V tile (wave-uniform LDS base).
#define STAGE_KV(T, BUF)                                                      \
  {                                                                           \
    const int kb_ = (T) * 64;                                                 \
    const int p = wave * 1024 + lane * 16;                                    \
    const int f = p ^ (((p >> 7) & 7) << 4);                                  \
    const int row = f >> 7, colb = f & 127;                                   \
    gload16(Kg + (size_t)(kb_ + row) * 2048 + colb,                           \
            (char*)Ksm[BUF] + wave * 1024);                                   \
    gload16(Vg + (size_t)row * 2048 + (size_t)kb_ * 2 + colb,                 \
            (char*)Vsm[BUF] + wave * 1024);                                   \
  }

  STAGE_KV(0, 0);
  __syncthreads();

  for (int t = 0; t < 16; ++t) {
    const int cb = t & 1;
    if (t < 15) STAGE_KV(t + 1, cb ^ 1);

    ushort4 mv[4];
#pragma unroll
    for (int fc = 0; fc < 4; ++fc)
      mv[fc] = Mb0[(size_t)(t * 16 + fc * 4 + lg) * 1024];

    f32x4 ts[4];
#pragma unroll
    for (int fc = 0; fc < 4; ++fc)
#pragma unroll
      for (int r = 0; r < 4; ++r) ts[fc][r] = 0.f;
    __builtin_amdgcn_s_setprio(1);
#pragma unroll
    for (int ks = 0; ks < 2; ++ks)
#pragma unroll
      for (int fc = 0; fc < 4; ++fc) {
        const int row = fc * 16 + lr;
        const int ad = ((row << 7) | (ks * 64 + lg * 16)) ^ ((row & 7) << 4);
        const bf16x8 kfr = *(const bf16x8*)((const char*)Ksm[cb] + ad);
        ts[fc] = mfma16(kfr, qf[ks], ts[fc]);
      }
    __builtin_amdgcn_s_setprio(0);

#pragma unroll
    for (int fc = 0; fc < 4; ++fc) {
      const float p0 = exp2f(ts[fc][0] + bf2f(mv[fc].x));
      const float p1 = exp2f(ts[fc][1] + bf2f(mv[fc].y));
      const float p2 = exp2f(ts[fc][2] + bf2f(mv[fc].z));
      const float p3 = exp2f(ts[fc][3] + bf2f(mv[fc].w));
      l += (p0 + p1) + (p2 + p3);
      unsigned int w0, w1;
      asm("v_cvt_pk_bf16_f32 %0, %1, %2" : "=v"(w0) : "v"(p0), "v"(p1));
      asm("v_cvt_pk_bf16_f32 %0, %1, %2" : "=v"(w1) : "v"(p2), "v"(p3));
      const int base = lr * 128 + fc * 32 + lg * 8;
      *(unsigned int*)(Pb + ((base + 0) ^ swx)) = w0;
      *(unsigned int*)(Pb + ((base + 4) ^ swx)) = w1;
    }

    __builtin_amdgcn_s_setprio(1);
#pragma unroll
    for (int ks = 0; ks < 2; ++ks) {
      const int ad = (lr * 128 + ks * 64 + lg * 16) ^ swx;
      const bf16x8 pa = *(const bf16x8*)(Pb + ad);
#pragma unroll
      for (int fc = 0; fc < 4; ++fc) {
        const int row = fc * 16 + lr;
        const int vad = ((row << 7) | (ks * 64 + lg * 16)) ^ ((row & 7) << 4);
        const bf16x8 vfr = *(const bf16x8*)((const char*)Vsm[cb] + vad);
        accO[fc] = mfma16(pa, vfr, accO[fc]);
      }
    }
    __builtin_amdgcn_s_setprio(0);

    __syncthreads();
  }

  l += __shfl_xor(l, 16);
  l += __shfl_xor(l, 32);
  float linv[4];
#pragma unroll
  for (int r = 0; r < 4; ++r) linv[r] = 1.0f / __shfl(l, lg * 4 + r);

  u16* Op = O + ((size_t)(b * 1024 + q0)) * 1024 + h * 64;
#pragma unroll
  for (int fc = 0; fc < 4; ++fc)
#pragma unroll
    for (int r = 0; r < 4; ++r)
      Op[(size_t)(lg * 4 + r) * 1024 + fc * 16 + lr] = f2bf(accO[fc][r] * linv[r]);
#undef STAGE_KV
}

// ---------------------------------------------------------------------------
// Fused transpose of the four 1024x1024 weights (f32 -> bf16, transposed).
// ---------------------------------------------------------------------------
__global__ __launch_bounds__(256)
void transpose4_kernel(const float* __restrict__ Wq, const float* __restrict__ Wk,
                       const float* __restrict__ Wv, const float* __restrict__ Wo,
                       u16* __restrict__ wqt, u16* __restrict__ wkt,
                       u16* __restrict__ wvt, u16* __restrict__ wot) {
  const int w = blockIdx.x >> 8, tile = blockIdx.x & 255;
  const float* in = (w == 0) ? Wq : (w == 1) ? Wk : (w == 2) ? Wv : Wo;
  u16* out = (w == 0) ? wqt : (w == 1) ? wkt : (w == 2) ? wvt : wot;
  __shared__ u16 t[64][65];
  const int bx = tile & 15, by = tile >> 4;
  const int tc = threadIdx.x & 63, t4 = threadIdx.x >> 6;
#pragma unroll
  for (int i = 0; i < 16; ++i) {
    const int r = i * 4 + t4;
    t[r][tc] = f2bf(in[(size_t)(by * 64 + r) * 1024 + bx * 64 + tc]);
  }
  __syncthreads();
#pragma unroll
  for (int i = 0; i < 16; ++i) {
    const int r = i * 4 + t4;
    out[(size_t)(bx * 64 + r) * 1024 + by * 64 + tc] = t[tc][r];
  }
}

// 64x64-tiled transpose + f32->bf16 cast: out[C][R] = bf16(in[R][C]^T)
__global__ __launch_bounds__(256)
void transpose_cast(const float* __restrict__ in, u16* __restrict__ out, int R, int C) {
  __shared__ u16 t[64][65];
  const int ctiles = C >> 6;
  const int bx = blockIdx.x % ctiles, by = blockIdx.x / ctiles;
  const int tc = threadIdx.x & 63, t4 = threadIdx.x >> 6;
#pragma unroll
  for (int i = 0; i < 16; ++i) {
    const int r = i * 4 + t4;
    t[r][tc] = f2bf(in[(size_t)(by * 64 + r) * C + bx * 64 + tc]);
  }
  __syncthreads();
#pragma unroll
  for (int i = 0; i < 16; ++i) {
    const int r = i * 4 + t4;
    out[(size_t)(bx * 64 + r) * R + by * 64 + tc] = t[tc][r];
  }
}

// int32 mask -> transposed interleaved additive-bf16 (exp2 domain)
__global__ __launch_bounds__(256)
void mask_t_kernel(const int* __restrict__ mask, u16* __restrict__ mt) {
  const int bt = blockIdx.x;
  const int b = bt >> 8;
  const int kt = (bt >> 4) & 15;
  const int qt = bt & 15;
  __shared__ u16 t[64][65];
  const int tc = threadIdx.x & 63, t4 = threadIdx.x >> 6;
  const u16 neg = f2bf(-1.442695040888963e9f);
  const int* src = mask + ((size_t)b * 1024 + qt * 64) * 1024 + kt * 64;
#pragma unroll
  for (int i = 0; i < 16; ++i) {
    const int q = i * 4 + t4;
    t[q][tc] = src[(size_t)q * 1024 + tc] ? (u16)0 : neg;
  }
  __syncthreads();
  ushort4* dst = (ushort4*)mt + ((size_t)b * 256 + kt * 16) * 1024 + qt * 64;
#pragma unroll
  for (int i = 0; i < 4; ++i) {
    const int kg = i * 4 + t4;
    ushort4 o;
    o.x = t[tc][kg * 4 + 0];
    o.y = t[tc][kg * 4 + 1];
    o.z = t[tc][kg * 4 + 2];
    o.w = t[tc][kg * 4 + 3];
    dst[(size_t)kg * 1024 + tc] = o;
  }
}

// Row LayerNorm over D=1024: f32 in, f32 gains, bf16 out
__global__ __launch_bounds__(256)
void ln_kernel(const float* __restrict__ x, const float* __restrict__ g,
               const float* __restrict__ bb, u16* __restrict__ y) {
  const int row = blockIdx.x, tid = threadIdx.x;
  const float4 v = ((const float4*)(x + (size_t)row * 1024))[tid];
  float s = v.x + v.y + v.z + v.w;
  float ss = v.x * v.x + v.y * v.y + v.z * v.z + v.w * v.w;
#pragma unroll
  for (int mk = 1; mk < 64; mk <<= 1) {
    s += __shfl_xor(s, mk);
    ss += __shfl_xor(ss, mk);
  }
  __shared__ float sa[4], sq[4];
  const int wave = tid >> 6, lane = tid & 63;
  if (lane == 0) { sa[wave] = s; sq[wave] = ss; }
  __syncthreads();
  s = sa[0] + sa[1] + sa[2] + sa[3];
  ss = sq[0] + sq[1] + sq[2] + sq[3];
  const float mu = s * 0.0009765625f;
  const float var = ss * 0.0009765625f - mu * mu;
  const float inv = rsqrtf(var + 1e-5f);
  const float4 gg = ((const float4*)g)[tid];
  const float4 bv = ((const float4*)bb)[tid];
  ushort4 o;
  o.x = f2bf((v.x - mu) * inv * gg.x + bv.x);
  o.y = f2bf((v.y - mu) * inv * gg.y + bv.y);
  o.z = f2bf((v.z - mu) * inv * gg.z + bv.z);
  o.w = f2bf((v.w - mu) * inv * gg.w + bv.w);
  *(ushort4*)(y + (size_t)row * 1024 + tid * 4) = o;
}

extern "C" void kernel_launch(void* const* d_in, const int* in_sizes, int n_in,
                              void* d_out, int out_size, void* d_ws, size_t ws_size,
                              hipStream_t stream) {
  (void)in_sizes; (void)n_in; (void)out_size; (void)ws_size;
  const float* x  = (const float*)d_in[0];
  const int* mask = (const int*)d_in[1];
  const float* Wq = (const float*)d_in[2];  const float* bq = (const float*)d_in[3];
  const float* Wk = (const float*)d_in[4];  const float* bk = (const float*)d_in[5];
  const float* Wv = (const float*)d_in[6];  const float* bv = (const float*)d_in[7];
  const float* Wo = (const float*)d_in[8];  const float* bo = (const float*)d_in[9];
  const float* W1 = (const float*)d_in[10]; const float* b1 = (const float*)d_in[11];
  const float* W2 = (const float*)d_in[12]; const float* b2 = (const float*)d_in[13];
  const float* g1 = (const float*)d_in[14]; const float* be1 = (const float*)d_in[15];
  const float* g2 = (const float*)d_in[16]; const float* be2 = (const float*)d_in[17];

  float* out = (float*)d_out;  // f32 residual stream x2 lives here

  u16* ws = (u16*)d_ws;
  const size_t M1 = (size_t)1024 * 1024;
  u16* y    = ws;
  u16* q    = ws + 8 * M1;
  u16* kbuf = ws + 16 * M1;
  u16* vbuf = ws + 24 * M1;      // attention output
  u16* vt   = ws + 32 * M1;      // V written transposed by the V-GEMM
  u16* hbuf = ws + 8 * M1;       // FFN mid over dead q/k/vbuf/vt
  u16* wqt  = ws + 40 * M1;
  u16* wkt  = ws + 41 * M1;
  u16* wvt  = ws + 42 * M1;
  u16* wot  = ws + 43 * M1;
  u16* w1t  = ws + 44 * M1;
  u16* w2t  = ws + 48 * M1;
  u16* maskT4 = y;               // mask lives in y while y is dead

  dim3 blk(256);
  dim3 blk8(512);
  transpose4_kernel<<<1024, blk, 0, stream>>>(Wq, Wk, Wv, Wo, wqt, wkt, wvt, wot);
  transpose_cast<<<1024, blk, 0, stream>>>(W1, w1t, 1024, 4096);
  transpose_cast<<<1024, blk, 0, stream>>>(W2, w2t, 4096, 1024);
  ln_kernel<<<8192, blk, 0, stream>>>(x, g1, be1, y);
  gemm8<3, 0, 2><<<256, blk8, 0, stream>>>(y, wqt, bq, nullptr, q, 8192, 1024, 1024);
  gemm8<0, 0, 2><<<256, blk8, 0, stream>>>(y, wkt, bk, nullptr, kbuf, 8192, 1024, 1024);
  gemm8<4, 0, 2><<<256, blk8, 0, stream>>>(y, wvt, bv, nullptr, vt, 8192, 1024, 1024);
  mask_t_kernel<<<2048, blk, 0, stream>>>(mask, maskT4);
  attn_kernel<<<1024, blk8, 0, stream>>>(q, kbuf, vt, maskT4, vbuf);
  gemm8<2, 1, 2><<<256, blk8, 0, stream>>>(vbuf, wot, bo, x, out, 8192, 1024, 1024);
  ln_kernel<<<8192, blk, 0, stream>>>(out, g2, be2, y);
  gemm8<1, 0, 4><<<512, blk8, 0, stream>>>(y, w1t, b1, nullptr, hbuf, 8192, 4096, 1024);
  gemm8<2, 1, 2><<<256, blk8, 0, stream>>>(hbuf, w2t, b2, out, out, 8192, 1024, 4096);
}

// Round 20
// 381.132 us; speedup vs baseline: 1.0649x; 1.0089x over previous
//
#include <hip/hip_runtime.h>
#include <math.h>

typedef unsigned short u16;
typedef short bf16x8 __attribute__((ext_vector_type(8)));
typedef float f32x4 __attribute__((ext_vector_type(4)));

#define DEV static __device__ __forceinline__

DEV float bf2f(u16 u) {
  union { unsigned int i; float f; } v; v.i = ((unsigned int)u) << 16; return v.f;
}
DEV u16 f2bf(float f) {
  union { float f; unsigned int i; } v; v.f = f;
  unsigned int x = v.i;
  return (u16)((x + 0x7FFFu + ((x >> 16) & 1u)) >> 16);  // RNE
}

DEV void gload16(const void* gsrc, void* ldst) {
  __builtin_amdgcn_global_load_lds(
      (__attribute__((address_space(1))) void*)gsrc,
      (__attribute__((address_space(3))) void*)ldst, 16, 0, 0);
}

DEV f32x4 mfma16(bf16x8 a, bf16x8 b, f32x4 c) {
  return __builtin_amdgcn_mfma_f32_16x16x32_bf16(a, b, c, 0, 0, 0);
}

// ---------------------------------------------------------------------------
// 8-phase 256-row NT GEMM — R8 structure + sound vmcnt "memory" clobbers
// (R15; pass pre+post). GEMM inner loop frozen since R15; epilogues vary.
// Stage stream (T0=2it, T1=T0+1; vmcnt(6) NFR=4 / vmcnt(4) NFR=2 at ph4/ph8;
// peeled final iteration drains once at ph4):
//  ph1 A(T1,h1) | ph2 B(T0+2,h0) | ph3 A(T0+2,h0) | ph4 B(T0+2,h1)+vm |
//  ph5 A(T0+2,h1) | ph6 B(T0+3,h0) | ph7 B(T0+3,h1) | ph8 A(T0+3,h0)+vm
// EPI: 0 bias, 1 +GELU(exp2-sigmoid), 2 +res(f32), 3 *QSCALE,
//      4 V-direct: write transposed to Vt[b][h][dk][s] (ushort4 per frag).
// ---------------------------------------------------------------------------
template <int EPI, int WF32, int NFR>
__global__ __launch_bounds__(512, 2)
void gemm8(const u16* __restrict__ A, const u16* __restrict__ Bt,
           const float* __restrict__ bias, const float* __restrict__ res,
           void* __restrict__ Cv, int M, int N, int K) {
  constexpr int BN = NFR * 64;
  constexpr int HB = NFR * 4096;  // B half-tile bytes (BN/2 rows x 128B)
  __shared__ __align__(16) char Alds[4 * 16384];
  __shared__ __align__(16) char Blds[4 * HB];

  const int ntn = N / BN;
  const int nwg = gridDim.x;          // multiple of 8 here
  const int cpx = nwg >> 3;
  const int bid = (int)blockIdx.x;
  const int swb = (bid & 7) * cpx + (bid >> 3);  // XCD-bijective swizzle
  const int tm = swb / ntn, tn = swb % ntn;

  const int tid = threadIdx.x;
  const int wave = tid >> 6, lane = tid & 63;
  const int wm = wave >> 2, wn = wave & 3;
  const int lg = lane >> 4, lr = lane & 15;
  const int swx = (lr & 7) << 4;

  f32x4 acc[8][NFR];
#pragma unroll
  for (int m = 0; m < 8; ++m)
#pragma unroll
    for (int n = 0; n < NFR; ++n)
#pragma unroll
      for (int r = 0; r < 4; ++r) acc[m][n][r] = 0.f;

  const size_t rowb = (size_t)K * 2;
  const char* Ab = (const char*)A + (size_t)tm * 256 * rowb;
  const char* Bb = (const char*)Bt + (size_t)tn * BN * rowb;

  int rowS[2], colS[2];
#pragma unroll
  for (int rr = 0; rr < 2; ++rr) {
    const int p = rr * 8192 + tid * 16;
    const int f = p ^ (((p >> 7) & 7) << 4);
    rowS[rr] = f >> 7; colS[rr] = f & 127;
  }

  const int NT = K >> 6;

#define SA(T, H)                                                              \
  do {                                                                        \
    char* d_ = Alds + ((((T) & 1) * 2 + (H)) << 14);                          \
    _Pragma("unroll")                                                         \
    for (int r_ = 0; r_ < 2; ++r_)                                            \
      gload16(Ab + (size_t)((H) * 128 + rowS[r_]) * rowb + (size_t)(T) * 128  \
                  + colS[r_],                                                 \
              d_ + r_ * 8192 + wave * 1024);                                  \
  } while (0)

#define SB(T, H)                                                              \
  do {                                                                        \
    char* d_ = Blds + ((((T) & 1) * 2 + (H)) * HB);                           \
    _Pragma("unroll")                                                         \
    for (int r_ = 0; r_ < NFR / 2; ++r_)                                      \
      gload16(Bb + (size_t)((H) * (BN / 2) + rowS[r_]) * rowb                 \
                  + (size_t)(T) * 128 + colS[r_],                             \
              d_ + r_ * 8192 + wave * 1024);                                  \
  } while (0)

  // DOVM: 0 none, 1 counted (6 for NFR=4 / 4 for NFR=2), 2 drain vmcnt(0)
#define PHASE(SS, Q, STG, DOVM)                                               \
  {                                                                           \
    if ((Q) == 0) {                                                           \
      _Pragma("unroll")                                                       \
      for (int n_ = 0; n_ < NFR; ++n_) {                                      \
        const int g_ = n_ * 4 + wn;                                           \
        const char* bs_ = Blds + ((SS) * 2 + g_ / (NFR * 2)) * HB;            \
        const int rb_ = (g_ % (NFR * 2)) * 16 + lr;                           \
        _Pragma("unroll")                                                     \
        for (int k_ = 0; k_ < 2; ++k_)                                        \
          bfr[n_][k_] =                                                       \
              *(const bf16x8*)(bs_ + ((rb_ * 128 + k_ * 64 + lg * 16) ^ swx));\
      }                                                                       \
    }                                                                         \
    bf16x8 af_[2][2];                                                         \
    {                                                                         \
      const char* as_ = Alds + (((SS) * 2 + ((Q) >> 1)) << 14);               \
      _Pragma("unroll")                                                       \
      for (int j_ = 0; j_ < 2; ++j_) {                                        \
        const int ra_ = ((4 * (Q) + 2 * j_ + wm) & 7) * 16 + lr;              \
        _Pragma("unroll")                                                     \
        for (int k_ = 0; k_ < 2; ++k_)                                        \
          af_[j_][k_] =                                                       \
              *(const bf16x8*)(as_ + ((ra_ * 128 + k_ * 64 + lg * 16) ^ swx));\
      }                                                                       \
    }                                                                         \
    STG;                                                                      \
    if ((Q) == 0) asm volatile("s_waitcnt lgkmcnt(8)");                       \
    if ((DOVM) == 1) {                                                        \
      if (NFR == 4) asm volatile("s_waitcnt vmcnt(6)" ::: "memory");          \
      else          asm volatile("s_waitcnt vmcnt(4)" ::: "memory");          \
    } else if ((DOVM) == 2) {                                                 \
      asm volatile("s_waitcnt vmcnt(0)" ::: "memory");                        \
    }                                                                         \
    __builtin_amdgcn_s_barrier();                                             \
    asm volatile("s_waitcnt lgkmcnt(0)");                                     \
    __builtin_amdgcn_sched_barrier(0);                                        \
    __builtin_amdgcn_s_setprio(1);                                            \
    _Pragma("unroll")                                                         \
    for (int j_ = 0; j_ < 2; ++j_)                                            \
      _Pragma("unroll")                                                       \
      for (int n_ = 0; n_ < NFR; ++n_)                                        \
        _Pragma("unroll")                                                     \
        for (int k_ = 0; k_ < 2; ++k_)                                        \
          acc[2 * (Q) + j_][n_] =                                             \
              mfma16(af_[j_][k_], bfr[n_][k_], acc[2 * (Q) + j_][n_]);        \
    __builtin_amdgcn_s_setprio(0);                                            \
    __builtin_amdgcn_s_barrier();                                             \
  }

  // prologue: tile0 complete + tile1 {A h0, B h0, B h1}; A(1,h1) at ph1.
  SA(0, 0); SA(0, 1); SB(0, 0); SB(0, 1); SA(1, 0); SB(1, 0); SB(1, 1);
  asm volatile("s_waitcnt vmcnt(0)" ::: "memory");
  __builtin_amdgcn_s_barrier();

  bf16x8 bfr[NFR][2];
  const int NIT = NT >> 1;
  for (int it = 0; it < NIT - 1; ++it) {
    const int T0 = 2 * it;
    PHASE(0, 0, SA(T0 + 1, 1), 0)
    PHASE(0, 1, SB(T0 + 2, 0), 0)
    PHASE(0, 2, SA(T0 + 2, 0), 0)
    PHASE(0, 3, SB(T0 + 2, 1), 1)
    PHASE(1, 0, SA(T0 + 2, 1), 0)
    PHASE(1, 1, SB(T0 + 3, 0), 0)
    PHASE(1, 2, SB(T0 + 3, 1), 0)
    PHASE(1, 3, SA(T0 + 3, 0), 1)
  }
  {  // peeled final iteration: stage only A(NT-1,h1); drain at ph4
    const int T0 = NT - 2;
    PHASE(0, 0, SA(T0 + 1, 1), 0)
    PHASE(0, 1, ((void)0), 0)
    PHASE(0, 2, ((void)0), 0)
    PHASE(0, 3, ((void)0), 2)
    PHASE(1, 0, ((void)0), 0)
    PHASE(1, 1, ((void)0), 0)
    PHASE(1, 2, ((void)0), 0)
    PHASE(1, 3, ((void)0), 0)
  }
#undef SA
#undef SB
#undef PHASE

  // Epilogue. D frag layout: row=(lane>>4)*4+r, col=lane&15 (verified).
#pragma unroll
  for (int m = 0; m < 8; ++m)
#pragma unroll
    for (int n = 0; n < NFR; ++n) {
      const int col = tn * BN + (n * 4 + wn) * 16 + lr;
      const float bc = bias[col];
      if (EPI == 4) {
        // V-direct: 4 r-values are 4 consecutive s positions -> one ushort4
        // at Vt[((b*16 + h)*64 + dk)*1024 + s0], 8B-aligned.
        const int row0 = tm * 256 + (2 * m + wm) * 16 + lg * 4;
        ushort4 o;
        o.x = f2bf(acc[m][n][0] + bc);
        o.y = f2bf(acc[m][n][1] + bc);
        o.z = f2bf(acc[m][n][2] + bc);
        o.w = f2bf(acc[m][n][3] + bc);
        const int b_ = row0 >> 10, s0 = row0 & 1023;
        u16* dst = (u16*)Cv +
                   ((size_t)((b_ << 4) + (col >> 6)) * 64 + (col & 63)) * 1024 + s0;
        *(ushort4*)dst = o;
        continue;
      }
#pragma unroll
      for (int r = 0; r < 4; ++r) {
        const int row = tm * 256 + (2 * m + wm) * 16 + lg * 4 + r;
        float vv = acc[m][n][r] + bc;
        if (EPI == 1) {
          // gelu_tanh(u) == u * sigmoid(2*c*(u+0.044715u^3)); exp2 domain.
          const float u = vv;
          const float z = u + 0.044715f * u * u * u;
          vv = u * __builtin_amdgcn_rcpf(1.0f + exp2f(-2.3022076954f * z));
        } else if (EPI == 2) {
          vv += res[(size_t)row * N + col];
        } else if (EPI == 3) {
          vv *= 0.180336880111112f;  // 0.125 * log2(e)
        }
        if (WF32)
          ((float*)Cv)[(size_t)row * N + col] = vv;
        else
          ((u16*)Cv)[(size_t)row * N + col] = f2bf(vv);
      }
    }
}

// ---------------------------------------------------------------------------
// Flash attention v5b (R19, pass): QBLK=128, 8 waves/wg, grid 1024,
// __launch_bounds__(512,4) -> 60 VGPR no-spill, LDS-limited 24 waves/CU.
// ---------------------------------------------------------------------------
__global__ __launch_bounds__(512, 4)
void attn_kernel(const u16* __restrict__ Q, const u16* __restrict__ Km,
                 const u16* __restrict__ Vt, const u16* __restrict__ maskT4,
                 u16* __restrict__ O) {
  const int bid = (int)blockIdx.x;
  const int swz = (bid & 7) * 128 + (bid >> 3);  // 1024 % 8 == 0: bijective
  const int qb = swz & 7;
  const int bh = swz >> 3;
  const int b = bh >> 4, h = bh & 15;
  const int wave = threadIdx.x >> 6, lane = threadIdx.x & 63;
  const int lg = lane >> 4, lr = lane & 15;
  __shared__ __align__(16) u16 Ksm[2][64 * 64];   // 16KB
  __shared__ __align__(16) u16 Vsm[2][64 * 64];   // 16KB
  __shared__ __align__(16) u16 Pl[8][1024];       // 16KB
  char* Pb = (char*)&Pl[wave][0];
  const int swx = (lr & 7) << 4;

  const int q0 = qb * 128 + wave * 16;
  const u16* Qp = Q + ((size_t)(b * 1024 + q0)) * 1024 + h * 64;
  bf16x8 qf[2];
#pragma unroll
  for (int ks = 0; ks < 2; ++ks)
    qf[ks] = *(const bf16x8*)(Qp + (size_t)lr * 1024 + ks * 32 + lg * 8);

  float l = 0.f;
  f32x4 accO[4];
#pragma unroll
  for (int fc = 0; fc < 4; ++fc)
#pragma unroll
    for (int r = 0; r < 4; ++r) accO[fc][r] = 0.f;

  const char* Kg = (const char*)(Km + (size_t)(b * 1024) * 1024 + h * 64);
  const char* Vg = (const char*)(Vt + (size_t)(bh * 64) * 1024);
  const ushort4* Mb0 = (const ushort4*)maskT4 + (size_t)b * 256 * 1024 + q0 + lr;

  // 8 waves x 1KB chunk each per K and V tile (wave-uniform LDS base).
#define STAGE_KV(T, BUF)                                                      \
  {                                                                           \
    const int kb_ = (T) * 64;                                                 \
    const int p = wave * 1024 + lane * 16;                                    \
    const int f = p ^ (((p >> 7) & 7) << 4);                                  \
    const int row = f >> 7, colb = f & 127;                                   \
    gload16(Kg + (size_t)(kb_ + row) * 2048 + colb,                           \
            (char*)Ksm[BUF] + wave * 1024);                                   \
    gload16(Vg + (size_t)row * 2048 + (size_t)kb_ * 2 + colb,                 \
            (char*)Vsm[BUF] + wave * 1024);                                   \
  }

  STAGE_KV(0, 0);
  __syncthreads();

  for (int t = 0; t < 16; ++t) {
    const int cb = t & 1;
    if (t < 15) STAGE_KV(t + 1, cb ^ 1);

    ushort4 mv[4];
#pragma unroll
    for (int fc = 0; fc < 4; ++fc)
      mv[fc] = Mb0[(size_t)(t * 16 + fc * 4 + lg) * 1024];

    f32x4 ts[4];
#pragma unroll
    for (int fc = 0; fc < 4; ++fc)
#pragma unroll
      for (int r = 0; r < 4; ++r) ts[fc][r] = 0.f;
    __builtin_amdgcn_s_setprio(1);
#pragma unroll
    for (int ks = 0; ks < 2; ++ks)
#pragma unroll
      for (int fc = 0; fc < 4; ++fc) {
        const int row = fc * 16 + lr;
        const int ad = ((row << 7) | (ks * 64 + lg * 16)) ^ ((row & 7) << 4);
        const bf16x8 kfr = *(const bf16x8*)((const char*)Ksm[cb] + ad);
        ts[fc] = mfma16(kfr, qf[ks], ts[fc]);
      }
    __builtin_amdgcn_s_setprio(0);

#pragma unroll
    for (int fc = 0; fc < 4; ++fc) {
      const float p0 = exp2f(ts[fc][0] + bf2f(mv[fc].x));
      const float p1 = exp2f(ts[fc][1] + bf2f(mv[fc].y));
      const float p2 = exp2f(ts[fc][2] + bf2f(mv[fc].z));
      const float p3 = exp2f(ts[fc][3] + bf2f(mv[fc].w));
      l += (p0 + p1) + (p2 + p3);
      unsigned int w0, w1;
      asm("v_cvt_pk_bf16_f32 %0, %1, %2" : "=v"(w0) : "v"(p0), "v"(p1));
      asm("v_cvt_pk_bf16_f32 %0, %1, %2" : "=v"(w1) : "v"(p2), "v"(p3));
      const int base = lr * 128 + fc * 32 + lg * 8;
      *(unsigned int*)(Pb + ((base + 0) ^ swx)) = w0;
      *(unsigned int*)(Pb + ((base + 4) ^ swx)) = w1;
    }

    __builtin_amdgcn_s_setprio(1);
#pragma unroll
    for (int ks = 0; ks < 2; ++ks) {
      const int ad = (lr * 128 + ks * 64 + lg * 16) ^ swx;
      const bf16x8 pa = *(const bf16x8*)(Pb + ad);
#pragma unroll
      for (int fc = 0; fc < 4; ++fc) {
        const int row = fc * 16 + lr;
        const int vad = ((row << 7) | (ks * 64 + lg * 16)) ^ ((row & 7) << 4);
        const bf16x8 vfr = *(const bf16x8*)((const char*)Vsm[cb] + vad);
        accO[fc] = mfma16(pa, vfr, accO[fc]);
      }
    }
    __builtin_amdgcn_s_setprio(0);

    __syncthreads();
  }

  l += __shfl_xor(l, 16);
  l += __shfl_xor(l, 32);
  float linv[4];
#pragma unroll
  for (int r = 0; r < 4; ++r) linv[r] = 1.0f / __shfl(l, lg * 4 + r);

  u16* Op = O + ((size_t)(b * 1024 + q0)) * 1024 + h * 64;
#pragma unroll
  for (int fc = 0; fc < 4; ++fc)
#pragma unroll
    for (int r = 0; r < 4; ++r)
      Op[(size_t)(lg * 4 + r) * 1024 + fc * 16 + lr] = f2bf(accO[fc][r] * linv[r]);
#undef STAGE_KV
}

// ---------------------------------------------------------------------------
// Unified weight prep: one launch transposes+casts all 6 weight matrices.
// Grid 3072 x 256: blocks 0..1023 = Wq/Wk/Wv/Wo (4 x 256 tiles of 1024^2),
// blocks 1024..2047 = W1 (1024x4096), blocks 2048..3071 = W2 (4096x1024).
// Same 64x64 LDS tile as the separate kernels; saves 2 launch overheads
// and one grid ramp-up/drain cycle.
// ---------------------------------------------------------------------------
__global__ __launch_bounds__(256)
void prep_kernel(const float* __restrict__ Wq, const float* __restrict__ Wk,
                 const float* __restrict__ Wv, const float* __restrict__ Wo,
                 const float* __restrict__ W1, const float* __restrict__ W2,
                 u16* __restrict__ wqt, u16* __restrict__ wkt,
                 u16* __restrict__ wvt, u16* __restrict__ wot,
                 u16* __restrict__ w1t, u16* __restrict__ w2t) {
  const int gb = (int)blockIdx.x;
  const float* in;
  u16* out;
  int R, C, tile;
  if (gb < 1024) {
    const int w = gb >> 8;
    in  = (w == 0) ? Wq : (w == 1) ? Wk : (w == 2) ? Wv : Wo;
    out = (w == 0) ? wqt : (w == 1) ? wkt : (w == 2) ? wvt : wot;
    R = 1024; C = 1024; tile = gb & 255;
  } else if (gb < 2048) {
    in = W1; out = w1t; R = 1024; C = 4096; tile = gb - 1024;
  } else {
    in = W2; out = w2t; R = 4096; C = 1024; tile = gb - 2048;
  }
  const int ctiles = C >> 6;
  const int bx = tile % ctiles, by = tile / ctiles;
  __shared__ u16 t[64][65];
  const int tc = threadIdx.x & 63, t4 = threadIdx.x >> 6;
#pragma unroll
  for (int i = 0; i < 16; ++i) {
    const int r = i * 4 + t4;
    t[r][tc] = f2bf(in[(size_t)(by * 64 + r) * C + bx * 64 + tc]);
  }
  __syncthreads();
#pragma unroll
  for (int i = 0; i < 16; ++i) {
    const int r = i * 4 + t4;
    out[(size_t)(bx * 64 + r) * R + by * 64 + tc] = t[tc][r];
  }
}

// int32 mask -> transposed interleaved additive-bf16 (exp2 domain)
__global__ __launch_bounds__(256)
void mask_t_kernel(const int* __restrict__ mask, u16* __restrict__ mt) {
  const int bt = blockIdx.x;
  const int b = bt >> 8;
  const int kt = (bt >> 4) & 15;
  const int qt = bt & 15;
  __shared__ u16 t[64][65];
  const int tc = threadIdx.x & 63, t4 = threadIdx.x >> 6;
  const u16 neg = f2bf(-1.442695040888963e9f);
  const int* src = mask + ((size_t)b * 1024 + qt * 64) * 1024 + kt * 64;
#pragma unroll
  for (int i = 0; i < 16; ++i) {
    const int q = i * 4 + t4;
    t[q][tc] = src[(size_t)q * 1024 + tc] ? (u16)0 : neg;
  }
  __syncthreads();
  ushort4* dst = (ushort4*)mt + ((size_t)b * 256 + kt * 16) * 1024 + qt * 64;
#pragma unroll
  for (int i = 0; i < 4; ++i) {
    const int kg = i * 4 + t4;
    ushort4 o;
    o.x = t[tc][kg * 4 + 0];
    o.y = t[tc][kg * 4 + 1];
    o.z = t[tc][kg * 4 + 2];
    o.w = t[tc][kg * 4 + 3];
    dst[(size_t)kg * 1024 + tc] = o;
  }
}

// Row LayerNorm over D=1024: f32 in, f32 gains, bf16 out
__global__ __launch_bounds__(256)
void ln_kernel(const float* __restrict__ x, const float* __restrict__ g,
               const float* __restrict__ bb, u16* __restrict__ y) {
  const int row = blockIdx.x, tid = threadIdx.x;
  const float4 v = ((const float4*)(x + (size_t)row * 1024))[tid];
  float s = v.x + v.y + v.z + v.w;
  float ss = v.x * v.x + v.y * v.y + v.z * v.z + v.w * v.w;
#pragma unroll
  for (int mk = 1; mk < 64; mk <<= 1) {
    s += __shfl_xor(s, mk);
    ss += __shfl_xor(ss, mk);
  }
  __shared__ float sa[4], sq[4];
  const int wave = tid >> 6, lane = tid & 63;
  if (lane == 0) { sa[wave] = s; sq[wave] = ss; }
  __syncthreads();
  s = sa[0] + sa[1] + sa[2] + sa[3];
  ss = sq[0] + sq[1] + sq[2] + sq[3];
  const float mu = s * 0.0009765625f;
  const float var = ss * 0.0009765625f - mu * mu;
  const float inv = rsqrtf(var + 1e-5f);
  const float4 gg = ((const float4*)g)[tid];
  const float4 bv = ((const float4*)bb)[tid];
  ushort4 o;
  o.x = f2bf((v.x - mu) * inv * gg.x + bv.x);
  o.y = f2bf((v.y - mu) * inv * gg.y + bv.y);
  o.z = f2bf((v.z - mu) * inv * gg.z + bv.z);
  o.w = f2bf((v.w - mu) * inv * gg.w + bv.w);
  *(ushort4*)(y + (size_t)row * 1024 + tid * 4) = o;
}

extern "C" void kernel_launch(void* const* d_in, const int* in_sizes, int n_in,
                              void* d_out, int out_size, void* d_ws, size_t ws_size,
                              hipStream_t stream) {
  (void)in_sizes; (void)n_in; (void)out_size; (void)ws_size;
  const float* x  = (const float*)d_in[0];
  const int* mask = (const int*)d_in[1];
  const float* Wq = (const float*)d_in[2];  const float* bq = (const float*)d_in[3];
  const float* Wk = (const float*)d_in[4];  const float* bk = (const float*)d_in[5];
  const float* Wv = (const float*)d_in[6];  const float* bv = (const float*)d_in[7];
  const float* Wo = (const float*)d_in[8];  const float* bo = (const float*)d_in[9];
  const float* W1 = (const float*)d_in[10]; const float* b1 = (const float*)d_in[11];
  const float* W2 = (const float*)d_in[12]; const float* b2 = (const float*)d_in[13];
  const float* g1 = (const float*)d_in[14]; const float* be1 = (const float*)d_in[15];
  const float* g2 = (const float*)d_in[16]; const float* be2 = (const float*)d_in[17];

  float* out = (float*)d_out;  // f32 residual stream x2 lives here

  u16* ws = (u16*)d_ws;
  const size_t M1 = (size_t)1024 * 1024;
  u16* y    = ws;
  u16* q    = ws + 8 * M1;
  u16* kbuf = ws + 16 * M1;
  u16* vbuf = ws + 24 * M1;      // attention output
  u16* vt   = ws + 32 * M1;      // V written transposed by the V-GEMM
  u16* hbuf = ws + 8 * M1;       // FFN mid over dead q/k/vbuf/vt
  u16* wqt  = ws + 40 * M1;
  u16* wkt  = ws + 41 * M1;
  u16* wvt  = ws + 42 * M1;
  u16* wot  = ws + 43 * M1;
  u16* w1t  = ws + 44 * M1;
  u16* w2t  = ws + 48 * M1;
  u16* maskT4 = y;               // mask lives in y while y is dead

  dim3 blk(256);
  dim3 blk8(512);
  prep_kernel<<<3072, blk, 0, stream>>>(Wq, Wk, Wv, Wo, W1, W2,
                                        wqt, wkt, wvt, wot, w1t, w2t);
  ln_kernel<<<8192, blk, 0, stream>>>(x, g1, be1, y);
  gemm8<3, 0, 2><<<256, blk8, 0, stream>>>(y, wqt, bq, nullptr, q, 8192, 1024, 1024);
  gemm8<0, 0, 2><<<256, blk8, 0, stream>>>(y, wkt, bk, nullptr, kbuf, 8192, 1024, 1024);
  gemm8<4, 0, 2><<<256, blk8, 0, stream>>>(y, wvt, bv, nullptr, vt, 8192, 1024, 1024);
  mask_t_kernel<<<2048, blk, 0, stream>>>(mask, maskT4);
  attn_kernel<<<1024, blk8, 0, stream>>>(q, kbuf, vt, maskT4, vbuf);
  gemm8<2, 1, 2><<<256, blk8, 0, stream>>>(vbuf, wot, bo, x, out, 8192, 1024, 1024);
  ln_kernel<<<8192, blk, 0, stream>>>(out, g2, be2, y);
  gemm8<1, 0, 4><<<512, blk8, 0, stream>>>(y, w1t, b1, nullptr, hbuf, 8192, 4096, 1024);
  gemm8<2, 1, 2><<<256, blk8, 0, stream>>>(hbuf, w2t, b2, out, out, 8192, 1024, 4096);
}